// Round 7
// baseline (27.945 us; speedup 1.0000x reference)
//
#include <hip/hip_runtime.h>
#include <math.h>

#define BATCH   32
#define SEQ     8192
#define HID     256
#define WIN     128
#define NSL     8            // window slices (blocks) per batch in K2
#define SLROWS  32           // window rows per slice
#define NQ      8            // j-slices per batch in K1
#define TPAD    260          // padded LDS tile row (floats)

// ws layout (bytes):
//   ws_pt  : double[BATCH*NQ]       @ 0       (2 KB)   j-slice partials of tanh@v_p
//   ws_exp : float[BATCH*256]       @ 2048    (32 KB)  unnormalized exp(score)
//   ws_sum : float[BATCH*NSL]       @ 34816   (1 KB)   per-slice exp sums
//   cnt    : int[BATCH*32]          @ 36864   (4 KB)   arrival counters, 128-B stride each
//   ws_ctx : float[BATCH*NSL*HID]   @ 40960   (256 KB) per-slice context partials
#define WS_PT_OFF   0
#define WS_EXP_OFF  2048
#define WS_SUM_OFF  34816
#define WS_CNT_OFF  36864
#define WS_CTX_OFF  40960

// ---------------------------------------------------------------------------
// K1: 256 blocks = 32 batches x 8 j-slices, 256 threads. (r6, proven)
// Zero 1/256 of attn_out + f64 partial of tanh(W_p h).v_p over 32 dims.
// ---------------------------------------------------------------------------
__global__ __launch_bounds__(256) void k1_pt(
    const float* __restrict__ h_t,    // [B, HID]
    const float* __restrict__ W_p,    // [HID, HID]
    const float* __restrict__ v_p,    // [HID]
    float* __restrict__ attn_out,     // [B, SEQ] (zeroed here)
    double* __restrict__ ws_pt)       // [B*NQ]
{
    const int blk = blockIdx.x;
    const int b   = blk >> 3;
    const int q   = blk & 7;
    const int tid = threadIdx.x;

    __shared__ float  hs[HID];
    __shared__ double red[256];

    hs[tid] = h_t[b * HID + tid];
    ((float4*)attn_out)[(size_t)blk * 256 + tid] = make_float4(0.f, 0.f, 0.f, 0.f);
    __syncthreads();

    const int jl = tid >> 3;
    const int j  = q * 32 + jl;
    const int ks = tid & 7;
    const float4* wrow = (const float4*)(W_p + (size_t)j * HID + ks * 32);
    const float*  h4   = &hs[ks * 32];
    double acc = 0.0;
#pragma unroll
    for (int k = 0; k < 8; ++k) {
        float4 w = wrow[k];
        acc += (double)w.x * h4[k*4+0] + (double)w.y * h4[k*4+1]
             + (double)w.z * h4[k*4+2] + (double)w.w * h4[k*4+3];
    }
    red[tid] = acc;
    __syncthreads();

    if (tid < 32) {
        double s = 0.0;
#pragma unroll
        for (int k = 0; k < 8; ++k) s += red[tid * 8 + k];
        float  t   = tanhf((float)s);
        double val = (double)t * (double)v_p[q * 32 + tid];
        for (int off = 16; off > 0; off >>= 1)
            val += __shfl_down(val, off, 32);
        if (tid == 0) ws_pt[b * NQ + q] = val;
    }
}

// ---------------------------------------------------------------------------
// K2_fused: 256 blocks = 32 batches x 8 slices, 256 threads.
// Slice work (r6 K2, proven) + last-arriving block of each batch finalizes.
// Sync fixes vs round 4: ONE threadfence per block (tid 0 only, after a
// vmcnt-draining __syncthreads), and each batch counter on its OWN 128-B
// cacheline (round 4 packed 32 counters into 2 lines -> serialized RMWs).
// ---------------------------------------------------------------------------
__global__ __launch_bounds__(256) void k2_fused(
    const float* __restrict__ enc,    // [B, SEQ, HID]
    const float* __restrict__ w_att,  // [HID]
    const double* __restrict__ ws_pt, // [B*NQ]
    float* __restrict__ ws_exp,       // [B*256]
    float* __restrict__ ws_sum,       // [B*NSL]
    float* __restrict__ ws_ctx,       // [B*NSL*HID]
    int*   __restrict__ counters,     // [B*32], 128-B stride
    float* __restrict__ ctx_out,      // [B, HID]
    float* __restrict__ attn_out)     // [B, SEQ]
{
    const int blk = blockIdx.x;
    const int b   = blk >> 3;
    const int s   = blk & 7;
    const int tid = threadIdx.x;

    __shared__ float  wa[HID];
    __shared__ float  tile[SLROWS][TPAD];
    __shared__ float  partial[256];
    __shared__ float  es[SLROWS];
    __shared__ double redd[NQ];
    __shared__ int    win_s[2];
    __shared__ int    is_last;
    __shared__ float  inv_s;

    wa[tid] = w_att[tid];
    if (tid < NQ) redd[tid] = ws_pt[b * NQ + tid];
    __syncthreads();
    if (tid == 0) {
        double x = 0.0;
#pragma unroll
        for (int k = 0; k < NQ; ++k) x += redd[k];
        float xf = (float)x;
        float sg = 1.0f / (1.0f + expf(-xf));      // sigmoid
        float p  = (float)SEQ * sg;
        int pr = (int)rintf(p);                    // round-half-even == jnp.round
        pr = min(max(pr, 0), SEQ - 1);
        win_s[0] = max(pr - WIN, 0);
        win_s[1] = min(pr + WIN, SEQ);
    }
    __syncthreads();

    const int start = win_s[0];
    const int end   = win_s[1];
    const int g0    = start + s * SLROWS;

    // ---- score pass + LDS staging (enc read once from HBM)
    {
        const int r  = tid >> 3;
        const int ks = tid & 7;
        const int g  = g0 + r;
        const int gc = (g < end) ? g : start;
        const float4* rowp = (const float4*)(enc + ((size_t)b * SEQ + gc) * HID + ks * 32);
        const float*  w4   = &wa[ks * 32];
        float4* trow = (float4*)&tile[r][ks * 32];
        float sc = 0.f;
#pragma unroll
        for (int k = 0; k < 8; ++k) {
            float4 e = rowp[k];
            trow[k] = e;
            sc += e.x * w4[k*4+0] + e.y * w4[k*4+1] + e.z * w4[k*4+2] + e.w * w4[k*4+3];
        }
        partial[tid] = sc;
    }
    __syncthreads();

    if (tid < SLROWS) {
        float scr = 0.f;
#pragma unroll
        for (int k = 0; k < 8; ++k) scr += partial[tid * 8 + k];
        const int g = g0 + tid;
        float ev = (g < end) ? expf(scr) : 0.f;    // no max-sub: scores ~N(0,1)
        es[tid] = ev;
        ws_exp[b * 256 + s * SLROWS + tid] = ev;
    }
    __syncthreads();

    if (tid == 0) {                                // fixed-order slice sum
        float sm = 0.f;
#pragma unroll
        for (int k = 0; k < SLROWS; ++k) sm += es[k];
        ws_sum[b * NSL + s] = sm;
    }

    // ---- ctx partial from LDS
    {
        float acc = 0.f;
#pragma unroll
        for (int i = 0; i < SLROWS; ++i)
            acc += es[i] * tile[i][tid];
        ws_ctx[((size_t)b * NSL + s) * HID + tid] = acc;
    }

    // ---- release + arrive (cheap form), last block finalizes
    __syncthreads();                               // every wave drains vmcnt here
    if (tid == 0) {
        __threadfence();                           // ONE wbL2 per block
        is_last = (atomicAdd(&counters[b * 32], 1) == NSL - 1);
    }
    __syncthreads();
    if (!is_last) return;

    __threadfence();                               // acquire: see other XCDs' partials

    if (tid == 0) {
        float dsum = 0.f;
#pragma unroll
        for (int k = 0; k < NSL; ++k) dsum += ws_sum[b * NSL + k];
        inv_s = 1.0f / dsum;
    }
    __syncthreads();

    const float inv = inv_s;
    float acc = 0.f;
#pragma unroll
    for (int k = 0; k < NSL; ++k)
        acc += ws_ctx[((size_t)b * NSL + k) * HID + tid];
    ctx_out[b * HID + tid] = acc * inv;

    const int L = end - start;
    if (tid < L)
        attn_out[(size_t)b * SEQ + start + tid] = ws_exp[b * 256 + tid] * inv;
}

extern "C" void kernel_launch(void* const* d_in, const int* in_sizes, int n_in,
                              void* d_out, int out_size, void* d_ws, size_t ws_size,
                              hipStream_t stream) {
    const float* h_t   = (const float*)d_in[0];   // [B, HID]
    const float* enc   = (const float*)d_in[1];   // [B, SEQ, HID]
    const float* W_p   = (const float*)d_in[2];   // [HID, HID]
    const float* v_p   = (const float*)d_in[3];   // [HID]
    const float* w_att = (const float*)d_in[4];   // [HID]

    float* ctx_out  = (float*)d_out;                  // [B, HID]
    float* attn_out = (float*)d_out + BATCH * HID;    // [B, SEQ]

    char*   ws       = (char*)d_ws;
    double* ws_pt    = (double*)(ws + WS_PT_OFF);
    float*  ws_exp   = (float*) (ws + WS_EXP_OFF);
    float*  ws_sum   = (float*) (ws + WS_SUM_OFF);
    int*    counters = (int*)   (ws + WS_CNT_OFF);
    float*  ws_ctx   = (float*) (ws + WS_CTX_OFF);

    hipMemsetAsync(counters, 0, BATCH * 32 * sizeof(int), stream);
    k1_pt<<<BATCH * NQ, 256, 0, stream>>>(h_t, W_p, v_p, attn_out, ws_pt);
    k2_fused<<<BATCH * NSL, 256, 0, stream>>>(
        enc, w_att, ws_pt, ws_exp, ws_sum, ws_ctx, counters, ctx_out, attn_out);
}

// Round 9
// 15.794 us; speedup vs baseline: 1.7694x; 1.7694x over previous
//
#include <hip/hip_runtime.h>
#include <math.h>

#define BATCH   32
#define SEQ     8192
#define HID     256
#define WIN     128
#define NSL     8            // window slices (blocks) per batch in K2
#define SLROWS  32           // window rows per slice
#define NQ      8            // j-slices per batch in K1
#define TPAD    260          // padded LDS tile row (floats)

// ws layout (bytes):
//   ws_pt  : double[BATCH*NQ]       @ 0       (2 KB)   j-slice partials of tanh@v_p
//   ws_exp : float[BATCH*256]       @ 2048    (32 KB)  unnormalized exp(score)
//   ws_sum : float[BATCH*NSL]       @ 34816   (1 KB)   per-slice exp sums
//   ws_ctx : float[BATCH*NSL*HID]   @ 35840   (256 KB) per-slice context partials
#define WS_PT_OFF   0
#define WS_EXP_OFF  2048
#define WS_SUM_OFF  34816
#define WS_CTX_OFF  35840

// ---------------------------------------------------------------------------
// K1: 256 blocks = 32 batches x 8 j-slices, 256 threads.
// Latency-slim: all global loads issued at entry (h_t read directly
// per-thread, L1-broadcast; no LDS staging barrier). One barrier total.
// ---------------------------------------------------------------------------
__global__ __launch_bounds__(256) void k1_pt(
    const float* __restrict__ h_t,    // [B, HID]
    const float* __restrict__ W_p,    // [HID, HID]
    const float* __restrict__ v_p,    // [HID]
    float* __restrict__ attn_out,     // [B, SEQ] (zeroed here)
    double* __restrict__ ws_pt)       // [B*NQ]
{
    const int blk = blockIdx.x;
    const int b   = blk >> 3;
    const int q   = blk & 7;
    const int tid = threadIdx.x;

    const int jl = tid >> 3;          // 0..31  (j within slice)
    const int j  = q * 32 + jl;
    const int ks = tid & 7;           // k-segment of 32 floats

    __shared__ double redj[32];

    // issue all independent loads up front
    const float4* wrow = (const float4*)(W_p + (size_t)j * HID + ks * 32);
    const float4* hrow = (const float4*)(h_t + (size_t)b * HID + ks * 32);
    float4 wv[8], hv[8];
#pragma unroll
    for (int k = 0; k < 8; ++k) wv[k] = wrow[k];
#pragma unroll
    for (int k = 0; k < 8; ++k) hv[k] = hrow[k];
    const float vpj = v_p[j];

    // zero attn: 65536 float4 over 65536 threads -> exactly one each (independent)
    ((float4*)attn_out)[(size_t)blk * 256 + tid] = make_float4(0.f, 0.f, 0.f, 0.f);

    double acc = 0.0;
#pragma unroll
    for (int k = 0; k < 8; ++k) {
        acc += (double)wv[k].x * (double)hv[k].x + (double)wv[k].y * (double)hv[k].y
             + (double)wv[k].z * (double)hv[k].z + (double)wv[k].w * (double)hv[k].w;
    }
    // 8-lane reduce (same j, consecutive lanes within a wave)
    acc += __shfl_down(acc, 4, 8);
    acc += __shfl_down(acc, 2, 8);
    acc += __shfl_down(acc, 1, 8);
    if (ks == 0) {
        float t = tanhf((float)acc);
        redj[jl] = (double)t * (double)vpj;
    }
    __syncthreads();
    if (tid < 32) {                   // all of wave 0
        double val = redj[tid];
        for (int off = 16; off > 0; off >>= 1)
            val += __shfl_down(val, off, 32);
        if (tid == 0) ws_pt[b * NQ + q] = val;
    }
}

// all-thread redundant window computation (identical arithmetic everywhere)
__device__ __forceinline__ void window_redundant(const double* __restrict__ ws_pt,
                                                 int b, int* start, int* end) {
    double x = 0.0;
#pragma unroll
    for (int k = 0; k < NQ; ++k) x += ws_pt[b * NQ + k];
    float xf = (float)x;
    float sg = 1.0f / (1.0f + expf(-xf));          // sigmoid
    float p  = (float)SEQ * sg;
    int pr = (int)rintf(p);                        // round-half-even == jnp.round
    pr = min(max(pr, 0), SEQ - 1);
    *start = max(pr - WIN, 0);
    *end   = min(pr + WIN, SEQ);
}

// ---------------------------------------------------------------------------
// K2: 256 blocks = 32 batches x 8 window-slices, 256 threads.
// Latency-slim: window computed redundantly by every thread (no barrier
// head); w_att read directly per-thread (L1-broadcast). Two barriers.
// ---------------------------------------------------------------------------
__global__ __launch_bounds__(256) void k2_scores_ctx(
    const float* __restrict__ enc,    // [B, SEQ, HID]
    const float* __restrict__ w_att,  // [HID]
    const double* __restrict__ ws_pt, // [B*NQ]
    float* __restrict__ ws_exp,       // [B*256]
    float* __restrict__ ws_sum,       // [B*NSL]
    float* __restrict__ ws_ctx)       // [B*NSL*HID]
{
    const int blk = blockIdx.x;
    const int b   = blk >> 3;
    const int s   = blk & 7;
    const int tid = threadIdx.x;

    __shared__ float tile[SLROWS][TPAD];
    __shared__ float partial[256];
    __shared__ float es[SLROWS];

    int start, end;
    window_redundant(ws_pt, b, &start, &end);      // every thread, no barrier
    const int g0 = start + s * SLROWS;

    // ---- score pass + LDS staging: 8 threads/row, 32-float segments
    {
        const int r  = tid >> 3;
        const int ks = tid & 7;
        const int g  = g0 + r;
        const int gc = (g < end) ? g : start;      // clamp (es=0 kills it later)
        const float4* rowp = (const float4*)(enc + ((size_t)b * SEQ + gc) * HID + ks * 32);
        const float4* wap  = (const float4*)(w_att + ks * 32);
        float4* trow = (float4*)&tile[r][ks * 32];
        float sc = 0.f;
#pragma unroll
        for (int k = 0; k < 8; ++k) {
            float4 e = rowp[k];
            float4 w = wap[k];
            trow[k] = e;
            sc += e.x * w.x + e.y * w.y + e.z * w.z + e.w * w.w;
        }
        partial[tid] = sc;
    }
    __syncthreads();

    if (tid < SLROWS) {                            // all of wave 0
        float scr = 0.f;
#pragma unroll
        for (int k = 0; k < 8; ++k) scr += partial[tid * 8 + k];
        const int g = g0 + tid;
        float ev = (g < end) ? expf(scr) : 0.f;    // no max-sub: scores ~N(0,1)
        es[tid] = ev;
        ws_exp[b * 256 + s * SLROWS + tid] = ev;
        // slice sum via in-wave shuffle (deterministic)
        float sm = ev;
        for (int off = 16; off > 0; off >>= 1)
            sm += __shfl_down(sm, off, 32);
        if (tid == 0) ws_sum[b * NSL + s] = sm;
    }
    __syncthreads();

    // ---- ctx partial from LDS tile: thread = h dim, 32 rows
    {
        float acc = 0.f;
#pragma unroll
        for (int i = 0; i < SLROWS; ++i)
            acc += es[i] * tile[i][tid];
        ws_ctx[((size_t)b * NSL + s) * HID + tid] = acc;
    }
}

// ---------------------------------------------------------------------------
// K3: 32 blocks x 256 threads, ZERO barriers. Every thread redundantly
// loads the small reductions (L1-broadcast) and its 8 ctx partials.
// ---------------------------------------------------------------------------
__global__ __launch_bounds__(256) void k3_finalize(
    const double* __restrict__ ws_pt,
    const float* __restrict__ ws_exp,
    const float* __restrict__ ws_sum,
    const float* __restrict__ ws_ctx,
    float* __restrict__ ctx_out,      // [B, HID]
    float* __restrict__ attn_out)     // [B, SEQ]
{
    const int b   = blockIdx.x;
    const int tid = threadIdx.x;

    // independent loads, all issued up front
    float cp[NSL];
#pragma unroll
    for (int k = 0; k < NSL; ++k)
        cp[k] = ws_ctx[((size_t)b * NSL + k) * HID + tid];

    float sums[NSL];
#pragma unroll
    for (int k = 0; k < NSL; ++k) sums[k] = ws_sum[b * NSL + k];

    int start, end;
    window_redundant(ws_pt, b, &start, &end);
    const float ev = ws_exp[b * 256 + tid];

    float dsum = 0.f;
#pragma unroll
    for (int k = 0; k < NSL; ++k) dsum += sums[k];
    const float inv = 1.0f / dsum;

    float acc = 0.f;
#pragma unroll
    for (int k = 0; k < NSL; ++k) acc += cp[k];
    ctx_out[b * HID + tid] = acc * inv;

    const int L = end - start;
    if (tid < L)
        attn_out[(size_t)b * SEQ + start + tid] = ev * inv;
}

extern "C" void kernel_launch(void* const* d_in, const int* in_sizes, int n_in,
                              void* d_out, int out_size, void* d_ws, size_t ws_size,
                              hipStream_t stream) {
    const float* h_t   = (const float*)d_in[0];   // [B, HID]
    const float* enc   = (const float*)d_in[1];   // [B, SEQ, HID]
    const float* W_p   = (const float*)d_in[2];   // [HID, HID]
    const float* v_p   = (const float*)d_in[3];   // [HID]
    const float* w_att = (const float*)d_in[4];   // [HID]

    float* ctx_out  = (float*)d_out;                  // [B, HID]
    float* attn_out = (float*)d_out + BATCH * HID;    // [B, SEQ]

    char*   ws     = (char*)d_ws;
    double* ws_pt  = (double*)(ws + WS_PT_OFF);
    float*  ws_exp = (float*) (ws + WS_EXP_OFF);
    float*  ws_sum = (float*) (ws + WS_SUM_OFF);
    float*  ws_ctx = (float*) (ws + WS_CTX_OFF);

    k1_pt<<<BATCH * NQ, 256, 0, stream>>>(h_t, W_p, v_p, attn_out, ws_pt);
    k2_scores_ctx<<<BATCH * NSL, 256, 0, stream>>>(enc, w_att, ws_pt, ws_exp, ws_sum, ws_ctx);
    k3_finalize<<<BATCH, 256, 0, stream>>>(ws_pt, ws_exp, ws_sum, ws_ctx, ctx_out, attn_out);
}